// Round 6
// baseline (494.737 us; speedup 1.0000x reference)
//
#include <hip/hip_runtime.h>

#define BB 64
#define QN 128
#define DD 512
#define EPSF 1e-8f
#define INFV 1e9f

// ---- cost: per-batch 64x64 tiles, 4x4 microtile, fused normalization ----
// cost[q,k] = -dot(r_q+eps, e_k+eps) / (max(||r_q+eps||,eps)*max(||e_k+eps||,eps))
__global__ __launch_bounds__(256) void cost_k(const float* __restrict__ rraw,
                                              const float* __restrict__ eraw,
                                              float* __restrict__ cost) {
  int b = blockIdx.y;
  int qt = (blockIdx.x >> 1) * 64;
  int kt = (blockIdx.x & 1) * 64;
  const float* R = rraw + ((size_t)b * QN + qt) * DD;
  const float* E = eraw + ((size_t)b * QN + kt) * DD;
  __shared__ float rsT[32][68];
  __shared__ float esT[32][68];
  __shared__ float sir[64], sie[64];  // 1/norm for the tile's rows/cols
  int tid = threadIdx.x;
  int tx = tid & 15, ty = tid >> 4;
  int lrow = tid >> 2;
  int ld = (tid & 3) * 8;
  float acc[4][4] = {};
  float rssq = 0.f, essq = 0.f;
  for (int d0 = 0; d0 < DD; d0 += 32) {
    float4 ra = *(const float4*)(R + (size_t)lrow * DD + d0 + ld);
    float4 rb = *(const float4*)(R + (size_t)lrow * DD + d0 + ld + 4);
    float4 ea = *(const float4*)(E + (size_t)lrow * DD + d0 + ld);
    float4 eb = *(const float4*)(E + (size_t)lrow * DD + d0 + ld + 4);
    ra.x += EPSF; ra.y += EPSF; ra.z += EPSF; ra.w += EPSF;
    rb.x += EPSF; rb.y += EPSF; rb.z += EPSF; rb.w += EPSF;
    ea.x += EPSF; ea.y += EPSF; ea.z += EPSF; ea.w += EPSF;
    eb.x += EPSF; eb.y += EPSF; eb.z += EPSF; eb.w += EPSF;
    rssq += ra.x * ra.x + ra.y * ra.y + ra.z * ra.z + ra.w * ra.w +
            rb.x * rb.x + rb.y * rb.y + rb.z * rb.z + rb.w * rb.w;
    essq += ea.x * ea.x + ea.y * ea.y + ea.z * ea.z + ea.w * ea.w +
            eb.x * eb.x + eb.y * eb.y + eb.z * eb.z + eb.w * eb.w;
    __syncthreads();
    rsT[ld + 0][lrow] = ra.x; rsT[ld + 1][lrow] = ra.y;
    rsT[ld + 2][lrow] = ra.z; rsT[ld + 3][lrow] = ra.w;
    rsT[ld + 4][lrow] = rb.x; rsT[ld + 5][lrow] = rb.y;
    rsT[ld + 6][lrow] = rb.z; rsT[ld + 7][lrow] = rb.w;
    esT[ld + 0][lrow] = ea.x; esT[ld + 1][lrow] = ea.y;
    esT[ld + 2][lrow] = ea.z; esT[ld + 3][lrow] = ea.w;
    esT[ld + 4][lrow] = eb.x; esT[ld + 5][lrow] = eb.y;
    esT[ld + 6][lrow] = eb.z; esT[ld + 7][lrow] = eb.w;
    __syncthreads();
#pragma unroll
    for (int dd = 0; dd < 32; ++dd) {
      float4 rv = *(const float4*)&rsT[dd][ty * 4];
      float4 ev = *(const float4*)&esT[dd][tx * 4];
      const float* rp = (const float*)&rv;
      const float* ep = (const float*)&ev;
#pragma unroll
      for (int ii = 0; ii < 4; ++ii)
#pragma unroll
        for (int jj = 0; jj < 4; ++jj) acc[ii][jj] += rp[ii] * ep[jj];
    }
  }
  // per-row sums of squares: 4 consecutive lanes share lrow
  rssq += __shfl_xor(rssq, 1, 64); rssq += __shfl_xor(rssq, 2, 64);
  essq += __shfl_xor(essq, 1, 64); essq += __shfl_xor(essq, 2, 64);
  if ((tid & 3) == 0) {
    sir[lrow] = 1.f / fmaxf(sqrtf(rssq), EPSF);
    sie[lrow] = 1.f / fmaxf(sqrtf(essq), EPSF);
  }
  __syncthreads();
  float irow[4], icol[4];
#pragma unroll
  for (int ii = 0; ii < 4; ++ii) { irow[ii] = sir[ty * 4 + ii]; icol[ii] = sie[tx * 4 + ii]; }
  float* Co = cost + ((size_t)b * QN + qt + ty * 4) * QN + kt + tx * 4;
#pragma unroll
  for (int ii = 0; ii < 4; ++ii) {
    float4 o = make_float4(-acc[ii][0] * irow[ii] * icol[0],
                           -acc[ii][1] * irow[ii] * icol[1],
                           -acc[ii][2] * irow[ii] * icol[2],
                           -acc[ii][3] * irow[ii] * icol[3]);
    *(float4*)(Co + (size_t)ii * QN) = o;
  }
}

// ---------------- DPP wave-64 min (result valid in lane 63) ----------------
template <int CTRL, int RM>
__device__ __forceinline__ float fmin_dpp(float x) {
  int y = __builtin_amdgcn_update_dpp(0x7f800000, __float_as_int(x), CTRL, RM,
                                      0xf, false);
  return fminf(x, __int_as_float(y));
}
__device__ __forceinline__ float wave_min63(float x) {
  x = fmin_dpp<0x111, 0xf>(x);  // row_shr:1
  x = fmin_dpp<0x112, 0xf>(x);  // row_shr:2
  x = fmin_dpp<0x114, 0xf>(x);  // row_shr:4
  x = fmin_dpp<0x118, 0xf>(x);  // row_shr:8
  x = fmin_dpp<0x142, 0xa>(x);  // row_bcast:15 -> rows 1,3
  x = fmin_dpp<0x143, 0xc>(x);  // row_bcast:31 -> rows 2,3
  return x;
}

__device__ __forceinline__ float rl_f(float x, int lane) {
  return __int_as_float(__builtin_amdgcn_readlane(__float_as_int(x), lane));
}

// ---------------- LSA: one wave per batch, all-register LAPJV -------------
// Lane t owns columns t and t+64 (v, minv, way, used, p) and rows t, t+64
// (u, matched-flag). Phases: column reduction -> greedy -> reduction
// transfer -> 2x augmenting row reduction -> SAP Dijkstra for leftovers.
__global__ __launch_bounds__(64) void lsa_k(const float* __restrict__ cost,
                                            float* __restrict__ col_out,
                                            float* __restrict__ part) {
  __shared__ float lC[QN * QN];  // 64 KB
  const int b = blockIdx.x;
  const int tid = threadIdx.x;
  const float* C = cost + (size_t)b * QN * QN;
  typedef const __attribute__((address_space(1))) void* gvp;
  typedef __attribute__((address_space(3))) void* svp;
#pragma unroll 4
  for (int k = 0; k < 64; ++k) {
    __builtin_amdgcn_global_load_lds((gvp)(C + k * 256 + tid * 4),
                                     (svp)(lC + k * 256), 16, 0, 0);
  }
  __syncthreads();

  // ---- init: column reduction ----
  float cmin0 = INFV, cmin1 = INFV;
  int am0 = 0, am1 = 0;
#pragma unroll 8
  for (int i = 0; i < QN; ++i) {
    float a = lC[i * QN + tid];
    float c = lC[i * QN + tid + 64];
    if (a < cmin0) { cmin0 = a; am0 = i; }
    if (c < cmin1) { cmin1 = c; am1 = i; }
  }
  float v0 = cmin0, v1 = cmin1;  // feasible duals: u=0, v=col min
  float ur0 = 0.f, ur1 = 0.f;
  int p0 = -1, p1 = -1;  // row matched to col tid / tid+64 (-1 free)
  int mr0 = 0, mr1 = 0;  // row tid / tid+64 matched flag

  // ---- greedy matching on zero reduced costs ----
  for (int j = 0; j < QN; ++j) {
    int r = __builtin_amdgcn_readlane(j < 64 ? am0 : am1, j & 63);
    int taken = __builtin_amdgcn_readlane(r < 64 ? mr0 : mr1, r & 63);
    if (!taken) {
      if (j < 64) { if (tid == j) p0 = r; }
      else        { if (tid == j - 64) p1 = r; }
      if (r < 64) { if (tid == r) mr0 = 1; }
      else        { if (tid == r - 64) mr1 = 1; }
    }
  }

  // ---- reduction transfer (LAPJV): tighten duals on matched rows ----
  // Matched arcs have c - v == 0 exactly; set u[i] = 2nd-min slack,
  // v[x[i]] -= u[i]. Keeps reduced costs >= 0, matched arcs == 0.
  for (int i = 0; i < QN; ++i) {
    int mi = __builtin_amdgcn_readlane(i < 64 ? mr0 : mr1, i & 63);
    if (!mi) continue;
    unsigned long long q0 = __ballot(p0 == i);
    unsigned long long q1 = __ballot(p1 == i);
    int j1 = q0 ? (__ffsll(q0) - 1) : (64 + __ffsll(q1) - 1);
    float c0 = lC[i * QN + tid];
    float c1 = lC[i * QN + tid + 64];
    float cur0 = (tid == j1) ? INFV : c0 - v0;
    float cur1 = (tid + 64 == j1) ? INFV : c1 - v1;
    float mu = rl_f(wave_min63(fminf(cur0, cur1)), 63);
    if (i < 64) { if (tid == i) ur0 = mu; }
    else        { if (tid == i - 64) ur1 = mu; }
    if (tid == j1) v0 -= mu;
    if (tid + 64 == j1) v1 -= mu;
  }

  // ---- augmenting row reduction (LAPJV), 2 passes ----
  for (int pass = 0; pass < 2; ++pass) {
    for (int i = 0; i < QN; ++i) {
      int mi = __builtin_amdgcn_readlane(i < 64 ? mr0 : mr1, i & 63);
      if (mi) continue;
      float c0 = lC[i * QN + tid];
      float c1 = lC[i * QN + tid + 64];
      float cur0 = c0 - v0;
      float cur1 = c1 - v1;
      float u1 = rl_f(wave_min63(fminf(cur0, cur1)), 63);
      unsigned long long bal0 = __ballot(cur0 == u1);
      unsigned long long bal1 = __ballot(cur1 == u1);
      int j1 = bal0 ? (__ffsll(bal0) - 1) : (64 + __ffsll(bal1) - 1);
      float mm0 = (tid == j1) ? INFV : cur0;
      float mm1 = (tid + 64 == j1) ? INFV : cur1;
      float u2 = rl_f(wave_min63(fminf(mm0, mm1)), 63);  // second min
      if (i < 64) { if (tid == i) ur0 = u2; }
      else        { if (tid == i - 64) ur1 = u2; }
      if (u1 < u2) {
        float dv = u2 - u1;
        if (tid == j1) v0 -= dv;
        if (tid + 64 == j1) v1 -= dv;
      } else {  // tie: prefer the second-argmin column if j1 is taken
        int pj = __builtin_amdgcn_readlane(j1 < 64 ? p0 : p1, j1 & 63);
        if (pj >= 0) {
          unsigned long long b20 = __ballot(mm0 == u2);
          unsigned long long b21 = __ballot(mm1 == u2);
          j1 = b20 ? (__ffsll(b20) - 1) : (64 + __ffsll(b21) - 1);
        }
      }
      int k = __builtin_amdgcn_readlane(j1 < 64 ? p0 : p1, j1 & 63);
      if (j1 < 64) { if (tid == j1) p0 = i; }
      else         { if (tid == j1 - 64) p1 = i; }
      if (i < 64) { if (tid == i) mr0 = 1; }
      else        { if (tid == i - 64) mr1 = 1; }
      if (k >= 0) {  // bumped row k becomes free again
        if (k < 64) { if (tid == k) mr0 = 0; }
        else        { if (tid == k - 64) mr1 = 0; }
      }
    }
  }

  // ---- Dijkstra augmentation for remaining free rows ----
  for (int i = 0; i < QN; ++i) {
    int mi = __builtin_amdgcn_readlane(i < 64 ? mr0 : mr1, i & 63);
    if (mi) continue;
    float minv0 = INFV, minv1 = INFV;
    int way0 = -1, way1 = -1;
    bool used0 = false, used1 = false;
    bool ract0 = (tid == i), ract1 = (tid + 64 == i);  // rows receiving delta
    int i0 = i;
    float c0 = lC[i0 * QN + tid];
    float c1 = lC[i0 * QN + tid + 64];
    float ui0 = rl_f(i0 < 64 ? ur0 : ur1, i0 & 63);
    int j0col = -1;  // -1 = virtual column
    int jfree;
    for (;;) {
      float cur0 = c0 - ui0 - v0;
      float cur1 = c1 - ui0 - v1;
      if (!used0 && cur0 < minv0) { minv0 = cur0; way0 = j0col; }
      if (!used1 && cur1 < minv1) { minv1 = cur1; way1 = j0col; }
      float m0 = used0 ? INFV : minv0;
      float m1 = used1 ? INFV : minv1;
      float red = wave_min63(fminf(m0, m1));
      float gv = rl_f(red, 63);
      unsigned long long bal0 = __ballot(m0 == gv);
      unsigned long long bal1 = __ballot(m1 == gv);
      int j1 = bal0 ? (__ffsll(bal0) - 1) : (64 + __ffsll(bal1) - 1);
      int pj1 = __builtin_amdgcn_readlane(j1 < 64 ? p0 : p1, j1 & 63);
      float delta = gv;
      if (pj1 >= 0) {
        i0 = pj1;
        c0 = lC[i0 * QN + tid];        // issue next row loads ASAP,
        c1 = lC[i0 * QN + tid + 64];   // overlap updates with LDS latency
        if (used0) v0 -= delta; else minv0 -= delta;
        if (used1) v1 -= delta; else minv1 -= delta;
        if (ract0) ur0 += delta;
        if (ract1) ur1 += delta;
        used0 = used0 || (tid == j1);
        used1 = used1 || (tid + 64 == j1);
        ract0 = ract0 || (tid == pj1);
        ract1 = ract1 || (tid + 64 == pj1);
        ui0 = rl_f(i0 < 64 ? ur0 : ur1, i0 & 63);  // pre-round value (row new)
        j0col = j1;
      } else {
        if (used0) v0 -= delta; else minv0 -= delta;
        if (used1) v1 -= delta; else minv1 -= delta;
        if (ract0) ur0 += delta;
        if (ract1) ur1 += delta;
        jfree = j1;
        break;
      }
    }
    // augment along way[] (uniform readlane chain + predicated lane writes)
    int j = jfree;
    for (;;) {
      int wj = __builtin_amdgcn_readlane(j < 64 ? way0 : way1, j & 63);
      int newp = (wj < 0) ? i
                          : __builtin_amdgcn_readlane(wj < 64 ? p0 : p1,
                                                      wj & 63);
      if (j < 64) { if (tid == j)      p0 = newp; }
      else        { if (tid == j - 64) p1 = newp; }
      if (wj < 0) break;
      j = wj;
    }
  }

  // col_ind[p[j]] = j ; sim[q] = -C[q, col[q]]
  col_out[(size_t)b * QN + p0] = (float)tid;
  col_out[(size_t)b * QN + p1] = (float)(tid + 64);
  float s = -lC[p0 * QN + tid] - lC[p1 * QN + tid + 64];
#pragma unroll
  for (int off = 32; off; off >>= 1) s += __shfl_xor(s, off, 64);
  if (tid == 0) part[b] = s;
}

// ---------------- loss epilogue ----------------
__global__ __launch_bounds__(64) void finish_k(const float* __restrict__ part,
                                               float* __restrict__ out) {
  int t = threadIdx.x;
  float val = 1.f - part[t] * (1.f / (float)QN);
#pragma unroll
  for (int off = 32; off; off >>= 1) val += __shfl_xor(val, off, 64);
  if (t == 0) out[0] = val * (1.f / (float)BB);
}

extern "C" void kernel_launch(void* const* d_in, const int* in_sizes, int n_in,
                              void* d_out, int out_size, void* d_ws, size_t ws_size,
                              hipStream_t stream) {
  const float* rub = (const float*)d_in[0];
  const float* euc = (const float*)d_in[1];
  float* out = (float*)d_out;
  float* ws = (float*)d_ws;
  float* cost = ws;                            // B*Q*Q
  float* part = cost + (size_t)BB * QN * QN;   // B

  dim3 gc(4, BB);
  cost_k<<<gc, 256, 0, stream>>>(rub, euc, cost);
  lsa_k<<<BB, 64, 0, stream>>>(cost, out + 1, part);
  finish_k<<<1, 64, 0, stream>>>(part, out);
}

// Round 7
// 376.317 us; speedup vs baseline: 1.3147x; 1.3147x over previous
//
#include <hip/hip_runtime.h>

#define BB 64
#define QN 128
#define DD 512
#define EPSF 1e-8f
#define INFV 1e9f

// ---- cost: per-batch 64x64 tiles, 4x4 microtile, fused normalization ----
// cost[q,k] = -dot(r_q+eps, e_k+eps) / (max(||r_q+eps||,eps)*max(||e_k+eps||,eps))
__global__ __launch_bounds__(256) void cost_k(const float* __restrict__ rraw,
                                              const float* __restrict__ eraw,
                                              float* __restrict__ cost,
                                              float* __restrict__ out) {
  if (blockIdx.x == 0 && blockIdx.y == 0 && threadIdx.x == 0)
    out[0] = 1.0f;  // base for the loss atomics in lsa_k
  int b = blockIdx.y;
  int qt = (blockIdx.x >> 1) * 64;
  int kt = (blockIdx.x & 1) * 64;
  const float* R = rraw + ((size_t)b * QN + qt) * DD;
  const float* E = eraw + ((size_t)b * QN + kt) * DD;
  __shared__ float rsT[32][68];
  __shared__ float esT[32][68];
  __shared__ float sir[64], sie[64];  // 1/norm for the tile's rows/cols
  int tid = threadIdx.x;
  int tx = tid & 15, ty = tid >> 4;
  int lrow = tid >> 2;
  int ld = (tid & 3) * 8;
  float acc[4][4] = {};
  float rssq = 0.f, essq = 0.f;
  for (int d0 = 0; d0 < DD; d0 += 32) {
    float4 ra = *(const float4*)(R + (size_t)lrow * DD + d0 + ld);
    float4 rb = *(const float4*)(R + (size_t)lrow * DD + d0 + ld + 4);
    float4 ea = *(const float4*)(E + (size_t)lrow * DD + d0 + ld);
    float4 eb = *(const float4*)(E + (size_t)lrow * DD + d0 + ld + 4);
    ra.x += EPSF; ra.y += EPSF; ra.z += EPSF; ra.w += EPSF;
    rb.x += EPSF; rb.y += EPSF; rb.z += EPSF; rb.w += EPSF;
    ea.x += EPSF; ea.y += EPSF; ea.z += EPSF; ea.w += EPSF;
    eb.x += EPSF; eb.y += EPSF; eb.z += EPSF; eb.w += EPSF;
    rssq += ra.x * ra.x + ra.y * ra.y + ra.z * ra.z + ra.w * ra.w +
            rb.x * rb.x + rb.y * rb.y + rb.z * rb.z + rb.w * rb.w;
    essq += ea.x * ea.x + ea.y * ea.y + ea.z * ea.z + ea.w * ea.w +
            eb.x * eb.x + eb.y * eb.y + eb.z * eb.z + eb.w * eb.w;
    __syncthreads();
    rsT[ld + 0][lrow] = ra.x; rsT[ld + 1][lrow] = ra.y;
    rsT[ld + 2][lrow] = ra.z; rsT[ld + 3][lrow] = ra.w;
    rsT[ld + 4][lrow] = rb.x; rsT[ld + 5][lrow] = rb.y;
    rsT[ld + 6][lrow] = rb.z; rsT[ld + 7][lrow] = rb.w;
    esT[ld + 0][lrow] = ea.x; esT[ld + 1][lrow] = ea.y;
    esT[ld + 2][lrow] = ea.z; esT[ld + 3][lrow] = ea.w;
    esT[ld + 4][lrow] = eb.x; esT[ld + 5][lrow] = eb.y;
    esT[ld + 6][lrow] = eb.z; esT[ld + 7][lrow] = eb.w;
    __syncthreads();
#pragma unroll
    for (int dd = 0; dd < 32; ++dd) {
      float4 rv = *(const float4*)&rsT[dd][ty * 4];
      float4 ev = *(const float4*)&esT[dd][tx * 4];
      const float* rp = (const float*)&rv;
      const float* ep = (const float*)&ev;
#pragma unroll
      for (int ii = 0; ii < 4; ++ii)
#pragma unroll
        for (int jj = 0; jj < 4; ++jj) acc[ii][jj] += rp[ii] * ep[jj];
    }
  }
  // per-row sums of squares: 4 consecutive lanes share lrow
  rssq += __shfl_xor(rssq, 1, 64); rssq += __shfl_xor(rssq, 2, 64);
  essq += __shfl_xor(essq, 1, 64); essq += __shfl_xor(essq, 2, 64);
  if ((tid & 3) == 0) {
    sir[lrow] = 1.f / fmaxf(sqrtf(rssq), EPSF);
    sie[lrow] = 1.f / fmaxf(sqrtf(essq), EPSF);
  }
  __syncthreads();
  float irow[4], icol[4];
#pragma unroll
  for (int ii = 0; ii < 4; ++ii) { irow[ii] = sir[ty * 4 + ii]; icol[ii] = sie[tx * 4 + ii]; }
  float* Co = cost + ((size_t)b * QN + qt + ty * 4) * QN + kt + tx * 4;
#pragma unroll
  for (int ii = 0; ii < 4; ++ii) {
    float4 o = make_float4(-acc[ii][0] * irow[ii] * icol[0],
                           -acc[ii][1] * irow[ii] * icol[1],
                           -acc[ii][2] * irow[ii] * icol[2],
                           -acc[ii][3] * irow[ii] * icol[3]);
    *(float4*)(Co + (size_t)ii * QN) = o;
  }
}

// ---------------- DPP wave-64 min (result valid in lane 63) ----------------
template <int CTRL, int RM>
__device__ __forceinline__ float fmin_dpp(float x) {
  int y = __builtin_amdgcn_update_dpp(0x7f800000, __float_as_int(x), CTRL, RM,
                                      0xf, false);
  return fminf(x, __int_as_float(y));
}
__device__ __forceinline__ float wave_min63(float x) {
  x = fmin_dpp<0x111, 0xf>(x);  // row_shr:1
  x = fmin_dpp<0x112, 0xf>(x);  // row_shr:2
  x = fmin_dpp<0x114, 0xf>(x);  // row_shr:4
  x = fmin_dpp<0x118, 0xf>(x);  // row_shr:8
  x = fmin_dpp<0x142, 0xa>(x);  // row_bcast:15 -> rows 1,3
  x = fmin_dpp<0x143, 0xc>(x);  // row_bcast:31 -> rows 2,3
  return x;
}

__device__ __forceinline__ float rl_f(float x, int lane) {
  return __int_as_float(__builtin_amdgcn_readlane(__float_as_int(x), lane));
}

// ---------------- LSA: one wave per batch, all-register LAPJV -------------
// Lane t owns columns t and t+64. pp packs (p[col t]+1) | (p[col t+64]+1)<<8
// (0 = free). u is ELIMINATED: fixed-dual Dijkstra with end-of-search v
// update (classic JV AUGMENT). Init: column reduction -> greedy -> 2x ARR.
__global__ __launch_bounds__(64) void lsa_k(const float* __restrict__ cost,
                                            float* __restrict__ col_out,
                                            float* __restrict__ out) {
  __shared__ float lC[QN * QN];  // 64 KB
  const int b = blockIdx.x;
  const int tid = threadIdx.x;
  const float* C = cost + (size_t)b * QN * QN;
  typedef const __attribute__((address_space(1))) void* gvp;
  typedef __attribute__((address_space(3))) void* svp;
#pragma unroll 4
  for (int k = 0; k < 64; ++k) {
    __builtin_amdgcn_global_load_lds((gvp)(C + k * 256 + tid * 4),
                                     (svp)(lC + k * 256), 16, 0, 0);
  }
  __syncthreads();

  // ---- init: column reduction ----
  float cmin0 = INFV, cmin1 = INFV;
  int am0 = 0, am1 = 0;
#pragma unroll 8
  for (int i = 0; i < QN; ++i) {
    float a = lC[i * QN + tid];
    float c = lC[i * QN + tid + 64];
    if (a < cmin0) { cmin0 = a; am0 = i; }
    if (c < cmin1) { cmin1 = c; am1 = i; }
  }
  float v0 = cmin0, v1 = cmin1;  // feasible duals: v = col min
  int pp = 0;                    // packed p: low byte col tid, high col tid+64
  int mr0 = 0, mr1 = 0;          // row tid / tid+64 matched flag

  // ---- greedy matching on zero reduced costs ----
  for (int j = 0; j < QN; ++j) {
    int r = __builtin_amdgcn_readlane(j < 64 ? am0 : am1, j & 63);
    int taken = __builtin_amdgcn_readlane(r < 64 ? mr0 : mr1, r & 63);
    if (!taken) {
      if (tid == (j & 63)) {
        if (j < 64) pp = (pp & 0xff00) | (r + 1);
        else        pp = (pp & 0x00ff) | ((r + 1) << 8);
      }
      if (r < 64) { if (tid == r) mr0 = 1; }
      else        { if (tid == r - 64) mr1 = 1; }
    }
  }

  // ---- augmenting row reduction (LAPJV), 2 passes ----
  for (int pass = 0; pass < 2; ++pass) {
    for (int i = 0; i < QN; ++i) {
      int mi = __builtin_amdgcn_readlane(i < 64 ? mr0 : mr1, i & 63);
      if (mi) continue;
      float c0 = lC[i * QN + tid];
      float c1 = lC[i * QN + tid + 64];
      float cur0 = c0 - v0;
      float cur1 = c1 - v1;
      float u1 = rl_f(wave_min63(fminf(cur0, cur1)), 63);
      unsigned long long bal0 = __ballot(cur0 == u1);
      unsigned long long bal1 = __ballot(cur1 == u1);
      int j1 = bal0 ? (__ffsll(bal0) - 1) : (64 + __ffsll(bal1) - 1);
      float mm0 = (tid == j1) ? INFV : cur0;
      float mm1 = (tid + 64 == j1) ? INFV : cur1;
      float u2 = rl_f(wave_min63(fminf(mm0, mm1)), 63);  // second min
      if (u1 < u2) {
        float dv = u2 - u1;
        if (tid == j1) v0 -= dv;
        if (tid + 64 == j1) v1 -= dv;
      } else {  // tie: prefer the second-argmin column if j1 is taken
        int pjB = __builtin_amdgcn_readlane(pp, j1 & 63);
        int pj = ((j1 < 64) ? (pjB & 0xff) : (pjB >> 8)) - 1;
        if (pj >= 0) {
          unsigned long long b20 = __ballot(mm0 == u2);
          unsigned long long b21 = __ballot(mm1 == u2);
          j1 = b20 ? (__ffsll(b20) - 1) : (64 + __ffsll(b21) - 1);
        }
      }
      int kB = __builtin_amdgcn_readlane(pp, j1 & 63);
      int k = ((j1 < 64) ? (kB & 0xff) : (kB >> 8)) - 1;
      if (tid == (j1 & 63)) {
        if (j1 < 64) pp = (pp & 0xff00) | (i + 1);
        else         pp = (pp & 0x00ff) | ((i + 1) << 8);
      }
      if (i < 64) { if (tid == i) mr0 = 1; }
      else        { if (tid == i - 64) mr1 = 1; }
      if (k >= 0) {  // bumped row k becomes free again
        if (k < 64) { if (tid == k) mr0 = 0; }
        else        { if (tid == k - 64) mr1 = 0; }
      }
    }
  }

  // ---- fixed-dual Dijkstra (u-free) for remaining free rows ----
  for (int i = 0; i < QN; ++i) {
    int mi = __builtin_amdgcn_readlane(i < 64 ? mr0 : mr1, i & 63);
    if (mi) continue;
    float d0 = lC[i * QN + tid] - v0;       // labels (u[f] shift irrelevant)
    float d1 = lC[i * QN + tid + 64] - v1;
    int way0 = -1, way1 = -1;
    bool used0 = false, used1 = false;
    float mu;
    int jfree;
    for (;;) {
      float m0 = used0 ? INFV : d0;
      float m1 = used1 ? INFV : d1;
      float red = wave_min63(fminf(m0, m1));
      mu = rl_f(red, 63);
      unsigned long long bal0 = __ballot(m0 == mu);
      unsigned long long bal1 = __ballot(m1 == mu);
      int j1 = bal0 ? (__ffsll(bal0) - 1) : (64 + __ffsll(bal1) - 1);
      int ppw = __builtin_amdgcn_readlane(pp, j1 & 63);
      int pj1 = ((j1 < 64) ? (ppw & 0xff) : (ppw >> 8)) - 1;
      if (pj1 < 0) { jfree = j1; break; }
      float c0 = lC[pj1 * QN + tid];        // issue loads ASAP
      float c1 = lC[pj1 * QN + tid + 64];
      used0 = used0 || (tid == j1);
      used1 = used1 || (tid + 64 == j1);
      float t0 = c0 - v0, t1 = c1 - v1;
      float base = rl_f(j1 < 64 ? t0 : t1, j1 & 63);  // matched-arc slack
      float s = mu - base;
      float nd0 = t0 + s, nd1 = t1 + s;
      if (!used0 && nd0 < d0) { d0 = nd0; way0 = j1; }
      if (!used1 && nd1 < d1) { d1 = nd1; way1 = j1; }
    }
    // end-of-search dual update: v[used] += d - mu  (<= 0)
    if (used0) v0 += d0 - mu;
    if (used1) v1 += d1 - mu;
    // augment along way[] (uniform readlane chain + predicated byte writes)
    int j = jfree;
    for (;;) {
      int wj = __builtin_amdgcn_readlane(j < 64 ? way0 : way1, j & 63);
      int newp;
      if (wj < 0) newp = i;
      else {
        int pw = __builtin_amdgcn_readlane(pp, wj & 63);
        newp = ((wj < 64) ? (pw & 0xff) : (pw >> 8)) - 1;
      }
      if (tid == (j & 63)) {
        if (j < 64) pp = (pp & 0xff00) | (newp + 1);
        else        pp = (pp & 0x00ff) | ((newp + 1) << 8);
      }
      if (wj < 0) break;
      j = wj;
    }
  }

  // col_ind[p[j]] = j ; sim[q] = -C[q, col[q]] ; loss via atomic
  int p0 = (pp & 0xff) - 1;
  int p1 = (pp >> 8) - 1;
  col_out[(size_t)b * QN + p0] = (float)tid;
  col_out[(size_t)b * QN + p1] = (float)(tid + 64);
  float s = -lC[p0 * QN + tid] - lC[p1 * QN + tid + 64];
#pragma unroll
  for (int off = 32; off; off >>= 1) s += __shfl_xor(s, off, 64);
  if (tid == 0) atomicAdd(out, -s * (1.0f / ((float)BB * (float)QN)));
}

extern "C" void kernel_launch(void* const* d_in, const int* in_sizes, int n_in,
                              void* d_out, int out_size, void* d_ws, size_t ws_size,
                              hipStream_t stream) {
  const float* rub = (const float*)d_in[0];
  const float* euc = (const float*)d_in[1];
  float* out = (float*)d_out;
  float* ws = (float*)d_ws;
  float* cost = ws;  // B*Q*Q

  dim3 gc(4, BB);
  cost_k<<<gc, 256, 0, stream>>>(rub, euc, cost, out);
  lsa_k<<<BB, 64, 0, stream>>>(cost, out + 1, out);
}